// Round 11
// baseline (117.343 us; speedup 1.0000x reference)
//
#include <hip/hip_runtime.h>
#include <hip/hip_bf16.h>
#include <stdint.h>

// GAT: B=4, N=2048, F_IN=F_OUT=256, H=4
#define H 4
#define BB 4
#define NN 2048
#define FIN 256
#define FOUT 256
#define M_TOT (BB*NN)   // 8192
#define LOG2E 1.44269504f

typedef float f32x4 __attribute__((ext_vector_type(4)));
typedef short s16x8 __attribute__((ext_vector_type(8)));
typedef unsigned int u32;

static __device__ __forceinline__ short f2bf(float f) {
    return __builtin_bit_cast(short, __float2bfloat16(f));
}
static __device__ __forceinline__ float bf2f(short u) {
    unsigned x = ((unsigned)(unsigned short)u) << 16;
    return __builtin_bit_cast(float, x);
}

// ---------------- prep (fused): W->WT (bf16), q = W.a, c = b.a ----------------
__global__ __launch_bounds__(256) void k_prep(const float* __restrict__ W, const float* __restrict__ a,
                                              const float* __restrict__ bvec,
                                              short* __restrict__ WT, float* __restrict__ q,
                                              float* __restrict__ c) {
    int bid = blockIdx.x;
    if (bid < 64) {
        __shared__ float lds[64][65];
        int h = bid >> 4, kt = (bid >> 2) & 3, ot = bid & 3;
        int kb = kt * 64, ob = ot * 64;
        int tx = threadIdx.x & 63, ty = threadIdx.x >> 6;
#pragma unroll
        for (int r = 0; r < 16; ++r) {
            int k_l = ty + r * 4;
            lds[tx][k_l] = W[(size_t)(h * FIN + kb + k_l) * FOUT + ob + tx];
        }
        __syncthreads();
#pragma unroll
        for (int r = 0; r < 16; ++r) {
            int o_l = ty + r * 4;
            WT[(size_t)(h * FOUT + ob + o_l) * FIN + kb + tx] = f2bf(lds[o_l][tx]);
        }
    } else if (bid < 320) {
        int wv = ((bid - 64) * 256 + threadIdx.x) >> 6;  // 0..1023
        int lane = threadIdx.x & 63;
        int h = wv >> 8, f = wv & 255;
        float4 w4 = *(const float4*)(W + (size_t)(h * FIN + f) * FOUT + lane * 4);
        float4 a4 = *(const float4*)(a + h * FOUT + lane * 4);
        float d = w4.x * a4.x + w4.y * a4.y + w4.z * a4.z + w4.w * a4.w;
#pragma unroll
        for (int off = 32; off; off >>= 1) d += __shfl_xor(d, off);
        if (lane == 0) q[h * FIN + f] = d;
    } else {
        int h = threadIdx.x >> 6, lane = threadIdx.x & 63;
        float4 b4 = *(const float4*)(bvec + h * FOUT + lane * 4);
        float4 a4 = *(const float4*)(a + h * FOUT + lane * 4);
        float d = b4.x * a4.x + b4.y * a4.y + b4.z * a4.z + b4.w * a4.w;
#pragma unroll
        for (int off = 32; off; off >>= 1) d += __shfl_xor(d, off);
        if (lane == 0) c[h] = d;
    }
}

// ---------------- scores (exact fp32) + X->bf16 conversion (fused) ----------------
__global__ __launch_bounds__(256) void k_s(const float* __restrict__ X, const float* __restrict__ q,
                                           const float* __restrict__ c, float* __restrict__ s,
                                           short* __restrict__ Xbf) {
    int m = blockIdx.x * 4 + (threadIdx.x >> 6);
    int lane = threadIdx.x & 63;
    float4 xv = *(const float4*)(X + (size_t)m * FIN + lane * 4);
    short4 xb;
    xb.x = f2bf(xv.x); xb.y = f2bf(xv.y); xb.z = f2bf(xv.z); xb.w = f2bf(xv.w);
    *(short4*)(Xbf + (size_t)m * FIN + lane * 4) = xb;
#pragma unroll
    for (int h = 0; h < H; ++h) {
        float4 qv = *(const float4*)(q + h * FIN + lane * 4);
        float d = xv.x * qv.x + xv.y * qv.y + xv.z * qv.z + xv.w * qv.w;
#pragma unroll
        for (int off = 32; off; off >>= 1) d += __shfl_xor(d, off);
        if (lane == 0) s[h * M_TOT + m] = d + c[h];
    }
}

// ---------------- bias -> mask bits + per-row masked max (s staged in LDS) ----------------
__global__ __launch_bounds__(256) void k_maskmax(const float* __restrict__ bias, const float* __restrict__ s,
                                                 unsigned* __restrict__ mask, float* __restrict__ mx) {
    __shared__ float sl[8192];   // 32KB
    int tid = threadIdx.x;
    int row0 = blockIdx.x * 4;
    int b = row0 >> 11;
#pragma unroll
    for (int i = 0; i < 8; ++i) {
        int flat = i * 1024 + tid * 4;
        int h = flat >> 11, j = flat & 2047;
        float4 v = *(const float4*)(s + (size_t)h * M_TOT + (size_t)b * NN + j);
        int phys = flat ^ (((flat >> 5) & 7) << 2);
        *(float4*)(sl + phys) = v;
    }
    __syncthreads();

    int w = tid >> 6, lane = tid & 63;
    int row = row0 + w;
    const float* bp = bias + (size_t)row * NN + lane * 32;
    unsigned bits = 0;
#pragma unroll
    for (int k = 0; k < 8; ++k) {
        float4 v = *(const float4*)(bp + k * 4);
        bits |= (v.x > -1.f ? 1u : 0u) << (k * 4 + 0);
        bits |= (v.y > -1.f ? 1u : 0u) << (k * 4 + 1);
        bits |= (v.z > -1.f ? 1u : 0u) << (k * 4 + 2);
        bits |= (v.w > -1.f ? 1u : 0u) << (k * 4 + 3);
    }
    mask[(size_t)row * 64 + lane] = bits;
#pragma unroll
    for (int h = 0; h < H; ++h) {
        float m = -3e38f;
#pragma unroll
        for (int k = 0; k < 8; ++k) {
            int flat = h * 2048 + lane * 32 + k * 4;
            int phys = flat ^ (((flat >> 5) & 7) << 2);
            float4 sv = *(const float4*)(sl + phys);
            m = fmaxf(m, ((bits >> (k * 4 + 0)) & 1u) ? sv.x : -3e38f);
            m = fmaxf(m, ((bits >> (k * 4 + 1)) & 1u) ? sv.y : -3e38f);
            m = fmaxf(m, ((bits >> (k * 4 + 2)) & 1u) ? sv.z : -3e38f);
            m = fmaxf(m, ((bits >> (k * 4 + 3)) & 1u) ? sv.w : -3e38f);
        }
#pragma unroll
        for (int off = 32; off; off >>= 1) m = fmaxf(m, __shfl_xor(m, off));
        if (lane == 0) mx[h * M_TOT + row] = m;
    }
}

// ---------------- tTs = bf16(X@W + b), stored FRAG-MAJOR ----------------
__global__ __launch_bounds__(256) void k_gemm_t(const short* __restrict__ WT, const short* __restrict__ Xbf,
                                                const float* __restrict__ bvec, short* __restrict__ tTs) {
    __shared__ short ot[64][136];   // bf16 D-tile [64 o][128 m], pad 8
    int h = blockIdx.z;
    int ob = blockIdx.y * 64;
    int mb = blockIdx.x * 128;
    int tid = threadIdx.x;
    int lane = tid & 63, w = tid >> 6;
    int r16 = lane & 15, g = lane >> 4;
    int mw = mb + w * 32;
    f32x4 acc[4][2] = {};
    for (int k = 0; k < FIN; k += 32) {
        s16x8 afr[4], bfr[2];
#pragma unroll
        for (int fa = 0; fa < 4; ++fa)
            afr[fa] = *(const s16x8*)(WT + (size_t)(h * FOUT + ob + fa * 16 + r16) * FIN + k + g * 8);
#pragma unroll
        for (int fb = 0; fb < 2; ++fb)
            bfr[fb] = *(const s16x8*)(Xbf + (size_t)(mw + fb * 16 + r16) * FIN + k + g * 8);
#pragma unroll
        for (int fa = 0; fa < 4; ++fa)
#pragma unroll
            for (int fb = 0; fb < 2; ++fb)
                acc[fa][fb] = __builtin_amdgcn_mfma_f32_16x16x32_bf16(afr[fa], bfr[fb], acc[fa][fb], 0, 0, 0);
    }
#pragma unroll
    for (int fa = 0; fa < 4; ++fa) {
#pragma unroll
        for (int r = 0; r < 4; ++r) {
            int o_l = fa * 16 + g * 4 + r;
            float bv = bvec[h * FOUT + ob + o_l];
#pragma unroll
            for (int fb = 0; fb < 2; ++fb)
                ot[o_l][w * 32 + fb * 16 + r16] = f2bf(acc[fa][fb][r] + bv);
        }
    }
    __syncthreads();
    int bb = mb >> 11, jloc = mb & 2047;
    int jt0 = jloc >> 6;
    size_t slab = (size_t)((h * 4 + bb) * 32) * 16384;
#pragma unroll
    for (int cc = 0; cc < 4; ++cc) {
        int sid = cc * 256 + tid;       // 0..1023
        int frag = sid >> 6;            // 0..15
        int l = sid & 63;
        int f_l = frag >> 2, jt_sel = (frag >> 1) & 1, par = frag & 1;
        int o_l = f_l * 16 + (l & 15);
        int m_l = jt_sel * 64 + par * 32 + (l >> 4) * 8;
        s16x8 v = *(const s16x8*)&ot[o_l][m_l];
        int fid = ((ob >> 4) + f_l) * 2 + par;
        size_t addr = slab + (size_t)(jt0 + jt_sel) * 16384 + fid * 512 + l * 8;
        *(s16x8*)(tTs + addr) = v;
    }
}

// ---------------- streaming softmax-PV: A-frags from L2, P via LDS ----------------
// 512 threads = 8 waves: par=w&1 (j-half 32), oh=w>>1 (o-quarter 64). q-block 64.
// Round-9-proven loop + algebraic 2FMA+max score chain. Epilogue: LDS-merged,
// coalesced OTn[h][m][o] stores (no scattered 2B global stores).
__global__ __launch_bounds__(512, 4) void k_attn(const short* __restrict__ tTs, const float* __restrict__ s,
                                                 const unsigned* __restrict__ mask, const float* __restrict__ mx,
                                                 short* __restrict__ OTn) {
    // bytes: [0,16384) P 2x8KB | epi: [0,33792) exf f32[64][132] ; [33792,67584) outT bf16[64][264] ; [67584,68096) pl
    __shared__ short smem[34048];   // 68096 B -> 2 blocks/CU

    // T1: bijective XCD swizzle (512 blocks)
    int flat = blockIdx.x + 32 * (blockIdx.y + 4 * blockIdx.z);
    int swz = (flat & 7) * 64 + (flat >> 3);
    int qt = swz & 31, b = (swz >> 5) & 3, h = swz >> 7;
    int ib = qt * 64;

    int tid = threadIdx.x;
    int lane = tid & 63, w = tid >> 6;
    int r16 = lane & 15, g = lane >> 4;
    int par = w & 1, oh = w >> 1;        // oh 0..3
    size_t gm = (size_t)b * NN;

    const short* slab = tTs + (size_t)((h * 4 + b) * 32) * 16384;
    const float* srow = s + h * M_TOT + gm;

    // P-production row: i = ib + oh*16 + r16
    int i = ib + oh * 16 + r16;
    float si = srow[i];
    float mxi = mx[h * M_TOT + gm + i];
    float z = si + mxi;
    float Mlog = fmaxf(z, 0.2f * z) * LOG2E;
    float siL = si * LOG2E;
    // aa = max(fma(sj,k1,c1), fma(sj,k2,c2))  ==  leaky((si+sj))*LOG2E - Mlog
    float c1 = siL - Mlog;
    float c2 = 0.2f * siL - Mlog;
    const float k1 = LOG2E, k2 = 0.2f * LOG2E;
    const unsigned* mk = mask + (gm + i) * 64;

    // P LDS offsets (shorts), XOR swizzle by row&7
    int chk = ((((par << 2) + g) ^ (r16 & 7)) << 3);
    int rdP = r16 * 64 + chk;                 // + qf*1024
    int wrP = oh * 1024 + rdP;

    f32x4 acc[4][4] = {};
    float lsum = 0.f;

    s16x8 acur[4], anext[4];
#pragma unroll
    for (int f = 0; f < 4; ++f)
        acur[f] = *(const s16x8*)(slab + ((oh * 4 + f) * 2 + par) * 512 + lane * 8);

    float4 psj0, psj1; unsigned pwm;
    {
        int jw = par * 32;
        psj0 = *(const float4*)(srow + jw + g * 8);
        psj1 = *(const float4*)(srow + jw + g * 8 + 4);
        pwm = mk[par];
    }

    for (int t = 0; t < 32; ++t) {
        if (t < 31) {
            const short* tp = slab + (size_t)(t + 1) * 16384;
#pragma unroll
            for (int f = 0; f < 4; ++f)
                anext[f] = *(const s16x8*)(tp + ((oh * 4 + f) * 2 + par) * 512 + lane * 8);
        }

        // ---- P production: 8 elems, row i, j = t*64 + par*32 + g*8 + e ----
        float sjv[8] = {psj0.x, psj0.y, psj0.z, psj0.w, psj1.x, psj1.y, psj1.z, psj1.w};
        unsigned bb0 = pwm >> (g * 8);
        s16x8 pb;
#pragma unroll
        for (int e = 0; e < 8; ++e) {
            float u = fmaf(sjv[e], k1, c1);
            float vv = fmaf(sjv[e], k2, c2);
            float aa = fmaxf(u, vv);
            aa = ((bb0 >> e) & 1u) ? aa : -200.f;  // <= 0 always
            float p = __builtin_amdgcn_exp2f(aa);
            lsum += p;
            pb[e] = f2bf(p);
        }
        *(s16x8*)(smem + (t & 1) * 4096 + wrP) = pb;

        if (t < 31) {
            int jw = (t + 1) * 64 + par * 32;
            psj0 = *(const float4*)(srow + jw + g * 8);
            psj1 = *(const float4*)(srow + jw + g * 8 + 4);
            pwm = mk[(t + 1) * 2 + par];
        }

        asm volatile("s_waitcnt lgkmcnt(0)" ::: "memory");
        __builtin_amdgcn_sched_barrier(0);
        __builtin_amdgcn_s_barrier();
        __builtin_amdgcn_sched_barrier(0);

        // ---- 4 P-frags x 4 A-frags = 16 MFMA ----
        const short* Pb = smem + (t & 1) * 4096;
        __builtin_amdgcn_s_setprio(1);
#pragma unroll
        for (int qf = 0; qf < 4; ++qf) {
            s16x8 pf = *(const s16x8*)(Pb + qf * 1024 + rdP);
            acc[0][qf] = __builtin_amdgcn_mfma_f32_16x16x32_bf16(acur[0], pf, acc[0][qf], 0, 0, 0);
            acc[1][qf] = __builtin_amdgcn_mfma_f32_16x16x32_bf16(acur[1], pf, acc[1][qf], 0, 0, 0);
            acc[2][qf] = __builtin_amdgcn_mfma_f32_16x16x32_bf16(acur[2], pf, acc[2][qf], 0, 0, 0);
            acc[3][qf] = __builtin_amdgcn_mfma_f32_16x16x32_bf16(acur[3], pf, acc[3][qf], 0, 0, 0);
        }
        __builtin_amdgcn_s_setprio(0);

        if (t < 31) {
#pragma unroll
            for (int f = 0; f < 4; ++f) acur[f] = anext[f];
        }
    }

    // ---- epilogue: merge par pairs in LDS, build out-tile, coalesced store ----
    __syncthreads();
    lsum += __shfl_xor(lsum, 16);
    lsum += __shfl_xor(lsum, 32);
    float* pl    = (float*)((char*)smem + 67584);
    float* plinv = pl + 64;
    if (par == 1 && g == 0) pl[oh * 16 + r16] = lsum;
    __syncthreads();
    if (par == 0 && g == 0) plinv[oh * 16 + r16] = 1.f / (lsum + pl[oh * 16 + r16]);
    __syncthreads();
    float linv[4];
#pragma unroll
    for (int qf = 0; qf < 4; ++qf) linv[qf] = plinv[qf * 16 + r16];

    float* exf  = (float*)smem;            // [64][132] f32
    short* outT = smem + 16896;            // [64][264] bf16
#pragma unroll
    for (int rnd = 0; rnd < 2; ++rnd) {
        if (par == 1 && (oh >> 1) == rnd) {
#pragma unroll
            for (int f = 0; f < 4; ++f)
#pragma unroll
                for (int qf = 0; qf < 4; ++qf) {
                    int irow = qf * 16 + r16;
                    int o_loc = (oh & 1) * 64 + f * 16 + g * 4;
                    *(f32x4*)(exf + irow * 132 + o_loc) = acc[f][qf];
                }
        }
        __syncthreads();
        if (par == 0 && (oh >> 1) == rnd) {
#pragma unroll
            for (int f = 0; f < 4; ++f)
#pragma unroll
                for (int qf = 0; qf < 4; ++qf) {
                    int irow = qf * 16 + r16;
                    int o_loc = (oh & 1) * 64 + f * 16 + g * 4;
                    f32x4 v = acc[f][qf] + *(const f32x4*)(exf + irow * 132 + o_loc);
                    short4 o4;
                    o4.x = f2bf(v[0] * linv[qf]); o4.y = f2bf(v[1] * linv[qf]);
                    o4.z = f2bf(v[2] * linv[qf]); o4.w = f2bf(v[3] * linv[qf]);
                    *(short4*)(outT + irow * 264 + rnd * 128 + o_loc) = o4;
                }
        }
        __syncthreads();
    }

    // coalesced copy-out: OTn[h][gm+ib+row][col..col+31]
    {
        int row = tid >> 3, col = (tid & 7) * 32;
        const short* src = outT + row * 264 + col;
        size_t gdst = ((size_t)h * M_TOT + gm + ib + row) * 256 + col;
#pragma unroll
        for (int cc = 0; cc < 4; ++cc)
            *(s16x8*)(OTn + gdst + cc * 8) = *(const s16x8*)(src + cc * 8);
    }
}

// ---------------- head mean (streaming, coalesced): out[m][o] = 0.25 * sum_h OTn[h][m][o] ----------------
__global__ __launch_bounds__(256) void k_reduce(const short* __restrict__ OTn, float* __restrict__ out) {
    size_t idx = ((size_t)blockIdx.x * 256 + threadIdx.x) * 8;
    float acc[8] = {};
#pragma unroll
    for (int h = 0; h < H; ++h) {
        s16x8 v = *(const s16x8*)(OTn + (size_t)h * M_TOT * 256 + idx);
#pragma unroll
        for (int e = 0; e < 8; ++e) acc[e] += bf2f(v[e]);
    }
    float4 o0, o1;
    o0.x = acc[0] * 0.25f; o0.y = acc[1] * 0.25f; o0.z = acc[2] * 0.25f; o0.w = acc[3] * 0.25f;
    o1.x = acc[4] * 0.25f; o1.y = acc[5] * 0.25f; o1.z = acc[6] * 0.25f; o1.w = acc[7] * 0.25f;
    *(float4*)(out + idx) = o0;
    *(float4*)(out + idx + 4) = o1;
}

extern "C" void kernel_launch(void* const* d_in, const int* in_sizes, int n_in,
                              void* d_out, int out_size, void* d_ws, size_t ws_size,
                              hipStream_t stream) {
    const float* X    = (const float*)d_in[0];  // [B,N,FIN]
    const float* bias = (const float*)d_in[1];  // [B,N,N]
    const float* W    = (const float*)d_in[2];  // [H,FIN,FOUT]
    const float* a    = (const float*)d_in[3];  // [H,FOUT]
    const float* bvec = (const float*)d_in[4];  // [H,FOUT]
    float* out = (float*)d_out;                 // [B,N,FOUT] f32

    // workspace layout (~40 MB high-water)
    char* ws = (char*)d_ws;
    short*    Xbf  = (short*)ws;                               //  4 MB  [8192][256] bf16
    short*    WT   = (short*)(ws + (4u << 20));                // 512 KB [H][256][256] bf16
    float*    q    = (float*)(ws + (4u << 20) + (768u << 10)); //  4 KB
    float*    c    = q + H * FIN;                              // 16 B
    float*    s    = (float*)(ws + (5u << 20));                // 128 KB [H][8192]
    float*    mxp  = (float*)(ws + (5u << 20) + (256u << 10)); // 128 KB [H][8192] row max
    short*    tTs  = (short*)(ws + (6u << 20));                // 16 MB  frag-major tiles
    short*    OTn  = (short*)(ws + (22u << 20));               // 16 MB  [H][8192][256] bf16
    unsigned* mask = (unsigned*)(ws + (38u << 20));            //  2 MB  [B][N][N/32] bits

    k_prep<<<321, 256, 0, stream>>>(W, a, bvec, WT, q, c);
    k_s<<<2048, 256, 0, stream>>>(X, q, c, s, Xbf);
    k_maskmax<<<2048, 256, 0, stream>>>(bias, s, mask, mxp);
    k_gemm_t<<<dim3(64, 4, 4), 256, 0, stream>>>(WT, Xbf, bvec, tTs);
    k_attn<<<dim3(32, 4, 4), 512, 0, stream>>>(tTs, s, mask, mxp, OTn);
    k_reduce<<<1024, 256, 0, stream>>>(OTn, out);
}